// Round 5
// baseline (641.822 us; speedup 1.0000x reference)
//
#include <hip/hip_runtime.h>
#include <hip/hip_fp16.h>

#define N_NODES_C 100000
#define N_EDGES_C 1600000
#define N_GRAPHS_C 2000
#define HID 128
#define BN_EPS_C 1e-5f
#define NBUCK 391          // ceil(100000 / 256) scan blocks

typedef _Float16 half8 __attribute__((ext_vector_type(8)));
typedef float float4v __attribute__((ext_vector_type(4)));

// ---------------- CSR build: direct scatter (no ebuf round-trip) ----------------

__global__ __launch_bounds__(256) void k_deg(const int* __restrict__ dst, int* __restrict__ deg) {
    const int base = blockIdx.x * 1024 + threadIdx.x;
    #pragma unroll
    for (int k = 0; k < 4; k++) {
        int e = base + k * 256;
        if (e < N_EDGES_C) atomicAdd(&deg[dst[e]], 1);
    }
}

// per-256-node block: exclusive scan of deg -> offs_local, block total -> btot
__global__ __launch_bounds__(256) void k_scan1(const int* __restrict__ deg,
                                               int* __restrict__ offs_local, int* __restrict__ btot) {
    __shared__ int s[256];
    const int t = threadIdx.x;
    const int node = blockIdx.x * 256 + t;
    int v = (node < N_NODES_C) ? deg[node] : 0;
    s[t] = v;
    __syncthreads();
    for (int off = 1; off < 256; off <<= 1) {
        int u = (t >= off) ? s[t - off] : 0;
        __syncthreads();
        s[t] += u;
        __syncthreads();
    }
    if (node < N_NODES_C) offs_local[node] = s[t] - v;
    if (t == 255) btot[blockIdx.x] = s[255];
}

// single block: exclusive scan of 391 block totals -> bbase
__global__ __launch_bounds__(512) void k_scan2(const int* __restrict__ btot, int* __restrict__ bbase) {
    __shared__ int s[512];
    const int t = threadIdx.x;
    int v = (t < NBUCK) ? btot[t] : 0;
    s[t] = v;
    __syncthreads();
    for (int off = 1; off < 512; off <<= 1) {
        int u = (t >= off) ? s[t - off] : 0;
        __syncthreads();
        s[t] += u;
        __syncthreads();
    }
    if (t < NBUCK) bbase[t] = s[t] - v;
}

__global__ __launch_bounds__(256) void k_fix(const int* __restrict__ deg, const int* __restrict__ offs_local,
                                             const int* __restrict__ bbase, int* __restrict__ offs,
                                             int* __restrict__ cursor, float* __restrict__ norm) {
    const int node = blockIdx.x * 256 + threadIdx.x;
    if (node < N_NODES_C) {
        int o = bbase[node >> 8] + offs_local[node];
        offs[node] = o;
        cursor[node] = o;
        norm[node] = rsqrtf((float)deg[node] + 1.0f);
    }
    if (node == 0) offs[N_NODES_C] = N_EDGES_C;
}

__global__ __launch_bounds__(256) void k_scatter(const int* __restrict__ src, const int* __restrict__ dst,
                                                 int* __restrict__ cursor, int* __restrict__ csr_src) {
    const int base = blockIdx.x * 1024 + threadIdx.x;
    #pragma unroll
    for (int k = 0; k < 4; k++) {
        int e = base + k * 256;
        if (e < N_EDGES_C) {
            int pos = atomicAdd(&cursor[dst[e]], 1);
            csr_src[pos] = src[e];
        }
    }
}

// ---------------- precompute: W -> fp16 transposed [n][k] ----------------

__global__ __launch_bounds__(256) void k_tw(const float* __restrict__ Ws_all, _Float16* __restrict__ WT) {
    int idx = blockIdx.x * 256 + threadIdx.x;     // 4*128*128 = 65536
    int l = idx >> 14, r = idx & 16383, k = r >> 7, n = r & 127;
    WT[l * 16384 + n * HID + k] = (_Float16)Ws_all[idx];
}

// ---------------- MFMA GEMM: Y[r,:] = norm[r] * (A[r,:] @ W), out fp16 ----------------
// F32A=true reads A rows as f32 (layer 0 consumes x directly). Rows with node >= nrows
// store ZEROS -> dummy zero row at index N_NODES without a separate memset.

template<bool F32A>
__global__ __launch_bounds__(256) void k_gemm(const void* __restrict__ Ap,
                                              const _Float16* __restrict__ WT,   // [128 n][128 k] fp16
                                              const float* __restrict__ norm,
                                              _Float16* __restrict__ Y, int nrows) {
    __shared__ _Float16 Wt[HID][136];   // [n][k], pitch 136 halves (272B: 2-way bank alias = free)
    const int tid = threadIdx.x;
    #pragma unroll
    for (int t = 0; t < 8; t++) {
        int off = tid * 8 + t * 2048;
        half8 v = *(const half8*)&WT[off];
        *(half8*)&Wt[off >> 7][off & 127] = v;
    }
    __syncthreads();

    const int wave = tid >> 6, lane = tid & 63, quad = lane >> 4, l16 = lane & 15;
    half8 Wf[2][4];
    #pragma unroll
    for (int c = 0; c < 2; c++)
        #pragma unroll
        for (int ks = 0; ks < 4; ks++)
            Wf[c][ks] = *(const half8*)&Wt[(wave * 2 + c) * 16 + l16][ks * 32 + quad * 8];

    const int nbase = blockIdx.x * 128;
    #pragma unroll
    for (int t = 0; t < 8; t++) {
        int node = nbase + t * 16 + l16;
        bool ok = node < nrows;
        half8 Af[4];
        if (F32A) {
            const float* arow = (const float*)Ap + (long)node * HID;
            #pragma unroll
            for (int ks = 0; ks < 4; ks++) {
                if (ok) {
                    float4 fa = *(const float4*)&arow[ks * 32 + quad * 8];
                    float4 fb = *(const float4*)&arow[ks * 32 + quad * 8 + 4];
                    _Float16 pk[8] = {(_Float16)fa.x, (_Float16)fa.y, (_Float16)fa.z, (_Float16)fa.w,
                                      (_Float16)fb.x, (_Float16)fb.y, (_Float16)fb.z, (_Float16)fb.w};
                    Af[ks] = *(half8*)pk;
                } else Af[ks] = half8{};
            }
        } else {
            const _Float16* arow = (const _Float16*)Ap + (long)node * HID;
            #pragma unroll
            for (int ks = 0; ks < 4; ks++)
                Af[ks] = ok ? *(const half8*)&arow[ks * 32 + quad * 8] : half8{};
        }
        float4v a0 = {0.f, 0.f, 0.f, 0.f}, a1 = {0.f, 0.f, 0.f, 0.f};
        #pragma unroll
        for (int ks = 0; ks < 4; ks++) {
            a0 = __builtin_amdgcn_mfma_f32_16x16x32_f16(Wf[0][ks], Af[ks], a0, 0, 0, 0);
            a1 = __builtin_amdgcn_mfma_f32_16x16x32_f16(Wf[1][ks], Af[ks], a1, 0, 0, 0);
        }
        float nv = ok ? norm[node] : 0.f;     // pad rows (incl. dummy row N_NODES) -> zeros
        _Float16 p0[4], p1[4];
        #pragma unroll
        for (int r = 0; r < 4; r++) {
            p0[r] = (_Float16)(a0[r] * nv);
            p1[r] = (_Float16)(a1[r] * nv);
        }
        *(ushort4*)&Y[(long)node * HID + (wave * 2 + 0) * 16 + quad * 4] = *(ushort4*)p0;
        *(ushort4*)&Y[(long)node * HID + (wave * 2 + 1) * 16 + quad * 4] = *(ushort4*)p1;
    }
}

// ---------------- Aggregation + bias + BN(eval) + ReLU ----------------
// r3 body (proven 58.6us): one wave per node, lane j handles channels (2j,2j+1) via half2.
// Edge indices wave-uniform -> scalar s_load; padded 16-edge chains with scalar cselect
// to a zeroed dummy row (row N_NODES). No serial tail, no vector masking.

__global__ __launch_bounds__(256) void k_agg(const __half* __restrict__ y, const int* __restrict__ offs,
                                             const int* __restrict__ csr_src, const float* __restrict__ norm,
                                             const float* __restrict__ bias, const float* __restrict__ mean,
                                             const float* __restrict__ gamma, const float* __restrict__ var,
                                             const float* __restrict__ beta, __half* __restrict__ h) {
    const int wave = __builtin_amdgcn_readfirstlane(threadIdx.x >> 6);
    const int lane = threadIdx.x & 63;
    const int i = blockIdx.x * 4 + wave;
    const int j = lane * 2;

    // self-loop term (y already scaled by norm[src] in k_gemm)
    float2 f = __half22float2(*(const __half2*)&y[(long)i * HID + j]);
    float acc0 = f.x, acc1 = f.y;

    const int e0 = offs[i], e1 = offs[i + 1];
    int e = e0;
    do {
        int id[16];
        #pragma unroll
        for (int u = 0; u < 16; u++) {
            int raw = csr_src[e + u];                    // scalar load (uniform addr, padded array)
            id[u] = (e + u < e1) ? raw : N_NODES_C;      // scalar cselect -> dummy zero row
        }
        #pragma unroll
        for (int u = 0; u < 16; u++) {
            float2 g = __half22float2(*(const __half2*)&y[(long)id[u] * HID + j]);
            acc0 += g.x; acc1 += g.y;
        }
        e += 16;
    } while (e < e1);

    const float ni = norm[i];
    float2 bi = *(const float2*)&bias[j];
    float2 me = *(const float2*)&mean[j];
    float2 ga = *(const float2*)&gamma[j];
    float2 va = *(const float2*)&var[j];
    float2 be = *(const float2*)&beta[j];
    float v0 = (acc0 * ni + bi.x - me.x) * (ga.x * rsqrtf(va.x + BN_EPS_C)) + be.x;
    float v1 = (acc1 * ni + bi.y - me.y) * (ga.y * rsqrtf(va.y + BN_EPS_C)) + be.y;
    *(__half2*)&h[(long)i * HID + j] = __floats2half2_rn(fmaxf(v0, 0.f), fmaxf(v1, 0.f));
}

// ---------------- Pooling (batch sorted -> run-length local accumulation) ----------------
// 32 nodes per block (3125 blocks) for occupancy; boundary runs merged via atomics.

__global__ __launch_bounds__(128) void k_pool(const __half* __restrict__ h, const int* __restrict__ batch,
                                              float* __restrict__ psum, int* __restrict__ pcount) {
    const int j = threadIdx.x;
    const int i0 = blockIdx.x * 32;
    const int iend = min(i0 + 32, N_NODES_C);
    if (i0 >= N_NODES_C) return;
    float acc = 0.f;
    int cur = batch[i0];
    int runStart = i0;
    for (int i = i0; i < iend; i++) {
        int g = batch[i];
        if (g != cur) {
            atomicAdd(&psum[(long)cur * HID + j], acc);
            if (j == 0) atomicAdd(&pcount[cur], i - runStart);
            acc = 0.f; cur = g; runStart = i;
        }
        acc += __half2float(h[(long)i * HID + j]);
    }
    atomicAdd(&psum[(long)cur * HID + j], acc);
    if (j == 0) atomicAdd(&pcount[cur], iend - runStart);
}

__global__ __launch_bounds__(128) void k_final(const float* __restrict__ psum, const int* __restrict__ pcount,
                                               const float* __restrict__ W_out, const float* __restrict__ b_out,
                                               float* __restrict__ out) {
    __shared__ float red[128][5];
    const int g = blockIdx.x, j = threadIdx.x;
    float cnt = fmaxf((float)pcount[g], 1.f);
    float p = psum[(long)g * HID + j] / cnt;
    #pragma unroll
    for (int o = 0; o < 5; o++) red[j][o] = p * W_out[j * 5 + o];
    __syncthreads();
    for (int off = 64; off >= 1; off >>= 1) {
        if (j < off) {
            #pragma unroll
            for (int o = 0; o < 5; o++) red[j][o] += red[j + off][o];
        }
        __syncthreads();
    }
    if (j < 5) out[g * 5 + j] = red[0][j] + b_out[j];
}

// ---------------- launch ----------------

extern "C" void kernel_launch(void* const* d_in, const int* in_sizes, int n_in,
                              void* d_out, int out_size, void* d_ws, size_t ws_size,
                              hipStream_t stream) {
    const float* x        = (const float*)d_in[0];
    const int*   eidx     = (const int*)d_in[1];
    const int*   src      = eidx;
    const int*   dst      = eidx + N_EDGES_C;
    const int*   batch    = (const int*)d_in[2];
    const float* Ws_all   = (const float*)d_in[3];
    const float* bs       = (const float*)d_in[4];
    const float* gammas   = (const float*)d_in[5];
    const float* betas    = (const float*)d_in[6];
    const float* run_mean = (const float*)d_in[7];
    const float* run_var  = (const float*)d_in[8];
    const float* W_out    = (const float*)d_in[9];
    const float* b_out    = (const float*)d_in[10];
    float* out = (float*)d_out;

    char* wp = (char*)d_ws;
    auto alloc = [&](size_t bytes) { char* p = wp; wp += (bytes + 255) & ~(size_t)255; return p; };
    __half*   h        = (__half*)alloc((size_t)N_NODES_C * HID * 2);
    _Float16* y        = (_Float16*)alloc((size_t)(N_NODES_C + 128) * HID * 2);  // +pad rows; dummy row N_NODES zeroed by k_gemm
    _Float16* WT       = (_Float16*)alloc((size_t)4 * HID * HID * 2);
    int*      csr_src  = (int*)alloc((size_t)(N_EDGES_C + 16) * 4);  // +16 pad for 16-wide chain overread (read, cselect-discarded)
    int*      offs     = (int*)alloc((size_t)(N_NODES_C + 1) * 4);
    float*    norm     = (float*)alloc((size_t)N_NODES_C * 4);
    int*      offs_loc = (int*)alloc((size_t)N_NODES_C * 4);
    int*      cursor   = (int*)alloc((size_t)N_NODES_C * 4);
    int*      btot     = (int*)alloc((NBUCK + 1) * 4);
    int*      bbase    = (int*)alloc((NBUCK + 1) * 4);
    // zero-init group: psum | pcount | deg contiguous -> ONE memset
    char*     zbeg     = wp;
    float*    psum     = (float*)alloc((size_t)N_GRAPHS_C * HID * 4);
    int*      pcount   = (int*)alloc((size_t)N_GRAPHS_C * 4);
    int*      deg      = (int*)alloc((size_t)N_NODES_C * 4);
    size_t    zlen     = (size_t)(wp - zbeg);

    hipMemsetAsync(zbeg, 0, zlen, stream);   // psum + pcount + deg in one shot

    k_tw<<<256, 256, 0, stream>>>(Ws_all, WT);

    const int EB = (N_EDGES_C + 1023) / 1024;   // 1563
    k_deg    <<<EB, 256, 0, stream>>>(dst, deg);
    k_scan1  <<<NBUCK, 256, 0, stream>>>(deg, offs_loc, btot);
    k_scan2  <<<1, 512, 0, stream>>>(btot, bbase);
    k_fix    <<<NBUCK, 256, 0, stream>>>(deg, offs_loc, bbase, offs, cursor, norm);
    k_scatter<<<EB, 256, 0, stream>>>(src, dst, cursor, csr_src);

    const int GB = (N_NODES_C + 127) / 128;   // 782
    const int AB = (N_NODES_C + 3) / 4;       // 25000
    for (int l = 0; l < 4; l++) {
        const void* A = (l == 0) ? (const void*)x : (const void*)h;
        if (l == 0)
            k_gemm<true><<<GB, 256, 0, stream>>>(A, WT, norm, y, N_NODES_C);
        else
            k_gemm<false><<<GB, 256, 0, stream>>>(A, WT + (size_t)l * HID * HID, norm, y, N_NODES_C);
        k_agg<<<AB, 256, 0, stream>>>((const __half*)y, offs, csr_src, norm,
                                      bs + l * HID, run_mean + l * HID, gammas + l * HID,
                                      run_var + l * HID, betas + l * HID, (__half*)h);
    }
    const int PB2 = (N_NODES_C + 31) / 32;    // 3125
    k_pool <<<PB2, 128, 0, stream>>>((const __half*)h, batch, psum, pcount);
    k_final<<<N_GRAPHS_C, 128, 0, stream>>>(psum, pcount, W_out, b_out, out);
}

// Round 6
// 501.993 us; speedup vs baseline: 1.2785x; 1.2785x over previous
//
#include <hip/hip_runtime.h>
#include <hip/hip_fp16.h>

#define N_NODES_C 100000
#define N_EDGES_C 1600000
#define N_GRAPHS_C 2000
#define HID 128
#define BN_EPS_C 1e-5f
#define NBUCK 391          // ceil(100000 / 256) buckets of 256 nodes
#define PART_TILE 4096     // edges per block in hist/partition kernels

typedef _Float16 half8 __attribute__((ext_vector_type(8)));
typedef float float4v __attribute__((ext_vector_type(4)));

// ---------------- CSR build: bucket partition (packed 4B ebuf) ----------------

__global__ __launch_bounds__(256) void kb_hist(const int* __restrict__ dst, int* __restrict__ bcount) {
    __shared__ int hist[NBUCK];
    const int t = threadIdx.x;
    for (int b = t; b < NBUCK; b += 256) hist[b] = 0;
    __syncthreads();
    const int e0 = blockIdx.x * PART_TILE;
    #pragma unroll
    for (int k = 0; k < 16; k++) {
        int e = e0 + k * 256 + t;
        if (e < N_EDGES_C) atomicAdd(&hist[dst[e] >> 8], 1);
    }
    __syncthreads();
    for (int b = t; b < NBUCK; b += 256) {
        int c = hist[b];
        if (c) atomicAdd(&bcount[b], c);
    }
}

__global__ __launch_bounds__(512) void kb_scan(const int* __restrict__ bcount,
                                               int* __restrict__ bbase, int* __restrict__ bcursor) {
    __shared__ int s[512];
    const int t = threadIdx.x;
    int v = (t < NBUCK) ? bcount[t] : 0;
    s[t] = v;
    __syncthreads();
    for (int off = 1; off < 512; off <<= 1) {
        int u = (t >= off) ? s[t - off] : 0;
        __syncthreads();
        s[t] += u;
        __syncthreads();
    }
    if (t < NBUCK) { int e = s[t] - v; bbase[t] = e; bcursor[t] = e; }
    if (t == 0) bbase[NBUCK] = N_EDGES_C;
}

// ebuf entry: (src << 8) | (dst & 255)  -- src < 2^17, fits with room to spare
__global__ __launch_bounds__(256) void kb_part(const int* __restrict__ src, const int* __restrict__ dst,
                                               int* __restrict__ bcursor, int* __restrict__ ebuf) {
    __shared__ int hist[NBUCK];
    __shared__ int startA[NBUCK];
    __shared__ int lcur[NBUCK];
    const int t = threadIdx.x;
    for (int b = t; b < NBUCK; b += 256) { hist[b] = 0; lcur[b] = 0; }
    __syncthreads();
    const int e0 = blockIdx.x * PART_TILE;
    #pragma unroll
    for (int k = 0; k < 16; k++) {
        int e = e0 + k * 256 + t;
        if (e < N_EDGES_C) atomicAdd(&hist[dst[e] >> 8], 1);
    }
    __syncthreads();
    for (int b = t; b < NBUCK; b += 256) {
        int c = hist[b];
        startA[b] = c ? atomicAdd(&bcursor[b], c) : 0;
    }
    __syncthreads();
    #pragma unroll
    for (int k = 0; k < 16; k++) {
        int e = e0 + k * 256 + t;
        if (e < N_EDGES_C) {
            int d = dst[e];
            int b = d >> 8;
            int pos = startA[b] + atomicAdd(&lcur[b], 1);
            ebuf[pos] = (src[e] << 8) | (d & 255);
        }
    }
}

// One block per bucket: local count+scan of 256 nodes -> offs, norm, csr_src (all writes bucket-local).
__global__ __launch_bounds__(256) void kb_fill(const int* __restrict__ ebuf, const int* __restrict__ bbase,
                                               int* __restrict__ csr_src, int* __restrict__ offs,
                                               float* __restrict__ norm) {
    __shared__ int s[256];
    __shared__ int excl[256];
    __shared__ int lcur[256];
    const int b = blockIdx.x, t = threadIdx.x;
    const int base = b << 8;
    const int e0 = bbase[b], e1 = bbase[b + 1];
    s[t] = 0; lcur[t] = 0;
    __syncthreads();
    for (int e = e0 + t; e < e1; e += 256)
        atomicAdd(&s[ebuf[e] & 255], 1);
    __syncthreads();
    int own = s[t];
    for (int off = 1; off < 256; off <<= 1) {
        int v = (t >= off) ? s[t - off] : 0;
        __syncthreads();
        s[t] += v;
        __syncthreads();
    }
    excl[t] = s[t] - own;
    int node = base + t;
    if (node < N_NODES_C) {
        offs[node] = e0 + (s[t] - own);
        norm[node] = rsqrtf((float)own + 1.0f);
    }
    if (b == 0 && t == 0) offs[N_NODES_C] = N_EDGES_C;
    __syncthreads();
    for (int e = e0 + t; e < e1; e += 256) {
        int p = ebuf[e];
        int l = p & 255;
        int pos = e0 + excl[l] + atomicAdd(&lcur[l], 1);
        csr_src[pos] = p >> 8;
    }
}

// ---------------- precompute: W -> fp16 transposed [n][k] ----------------

__global__ __launch_bounds__(256) void k_tw(const float* __restrict__ Ws_all, _Float16* __restrict__ WT) {
    int idx = blockIdx.x * 256 + threadIdx.x;     // 4*128*128 = 65536
    int l = idx >> 14, r = idx & 16383, k = r >> 7, n = r & 127;
    WT[l * 16384 + n * HID + k] = (_Float16)Ws_all[idx];
}

// ---------------- MFMA GEMM: Y[r,:] = norm[r] * (A[r,:] @ W), out fp16 ----------------
// F32A=true reads A rows as f32 (layer 0 consumes x directly). Rows with node >= nrows
// store ZEROS -> dummy zero row at index N_NODES without a separate memset.

template<bool F32A>
__global__ __launch_bounds__(256) void k_gemm(const void* __restrict__ Ap,
                                              const _Float16* __restrict__ WT,   // [128 n][128 k] fp16
                                              const float* __restrict__ norm,
                                              _Float16* __restrict__ Y, int nrows) {
    __shared__ _Float16 Wt[HID][136];   // [n][k], pitch 136 halves (272B: 2-way bank alias = free)
    const int tid = threadIdx.x;
    #pragma unroll
    for (int t = 0; t < 8; t++) {
        int off = tid * 8 + t * 2048;
        half8 v = *(const half8*)&WT[off];
        *(half8*)&Wt[off >> 7][off & 127] = v;
    }
    __syncthreads();

    const int wave = tid >> 6, lane = tid & 63, quad = lane >> 4, l16 = lane & 15;
    half8 Wf[2][4];
    #pragma unroll
    for (int c = 0; c < 2; c++)
        #pragma unroll
        for (int ks = 0; ks < 4; ks++)
            Wf[c][ks] = *(const half8*)&Wt[(wave * 2 + c) * 16 + l16][ks * 32 + quad * 8];

    const int nbase = blockIdx.x * 128;
    #pragma unroll
    for (int t = 0; t < 8; t++) {
        int node = nbase + t * 16 + l16;
        bool ok = node < nrows;
        half8 Af[4];
        if (F32A) {
            const float* arow = (const float*)Ap + (long)node * HID;
            #pragma unroll
            for (int ks = 0; ks < 4; ks++) {
                if (ok) {
                    float4 fa = *(const float4*)&arow[ks * 32 + quad * 8];
                    float4 fb = *(const float4*)&arow[ks * 32 + quad * 8 + 4];
                    _Float16 pk[8] = {(_Float16)fa.x, (_Float16)fa.y, (_Float16)fa.z, (_Float16)fa.w,
                                      (_Float16)fb.x, (_Float16)fb.y, (_Float16)fb.z, (_Float16)fb.w};
                    Af[ks] = *(half8*)pk;
                } else Af[ks] = half8{};
            }
        } else {
            const _Float16* arow = (const _Float16*)Ap + (long)node * HID;
            #pragma unroll
            for (int ks = 0; ks < 4; ks++)
                Af[ks] = ok ? *(const half8*)&arow[ks * 32 + quad * 8] : half8{};
        }
        float4v a0 = {0.f, 0.f, 0.f, 0.f}, a1 = {0.f, 0.f, 0.f, 0.f};
        #pragma unroll
        for (int ks = 0; ks < 4; ks++) {
            a0 = __builtin_amdgcn_mfma_f32_16x16x32_f16(Wf[0][ks], Af[ks], a0, 0, 0, 0);
            a1 = __builtin_amdgcn_mfma_f32_16x16x32_f16(Wf[1][ks], Af[ks], a1, 0, 0, 0);
        }
        float nv = ok ? norm[node] : 0.f;     // pad rows (incl. dummy row N_NODES) -> zeros
        _Float16 p0[4], p1[4];
        #pragma unroll
        for (int r = 0; r < 4; r++) {
            p0[r] = (_Float16)(a0[r] * nv);
            p1[r] = (_Float16)(a1[r] * nv);
        }
        *(ushort4*)&Y[(long)node * HID + (wave * 2 + 0) * 16 + quad * 4] = *(ushort4*)p0;
        *(ushort4*)&Y[(long)node * HID + (wave * 2 + 1) * 16 + quad * 4] = *(ushort4*)p1;
    }
}

// ---------------- Aggregation + bias + BN(eval) + ReLU ----------------
// r3 body (proven 58.6us): one wave per node, lane j handles channels (2j,2j+1) via half2.
// Edge indices wave-uniform -> scalar s_load; padded 16-edge chains with scalar cselect
// to a zeroed dummy row (row N_NODES). No serial tail, no vector masking.

__global__ __launch_bounds__(256) void k_agg(const __half* __restrict__ y, const int* __restrict__ offs,
                                             const int* __restrict__ csr_src, const float* __restrict__ norm,
                                             const float* __restrict__ bias, const float* __restrict__ mean,
                                             const float* __restrict__ gamma, const float* __restrict__ var,
                                             const float* __restrict__ beta, __half* __restrict__ h) {
    const int wave = __builtin_amdgcn_readfirstlane(threadIdx.x >> 6);
    const int lane = threadIdx.x & 63;
    const int i = blockIdx.x * 4 + wave;
    const int j = lane * 2;

    // self-loop term (y already scaled by norm[src] in k_gemm)
    float2 f = __half22float2(*(const __half2*)&y[(long)i * HID + j]);
    float acc0 = f.x, acc1 = f.y;

    const int e0 = offs[i], e1 = offs[i + 1];
    int e = e0;
    do {
        int id[16];
        #pragma unroll
        for (int u = 0; u < 16; u++) {
            int raw = csr_src[e + u];                    // scalar load (uniform addr, padded array)
            id[u] = (e + u < e1) ? raw : N_NODES_C;      // scalar cselect -> dummy zero row
        }
        #pragma unroll
        for (int u = 0; u < 16; u++) {
            float2 g = __half22float2(*(const __half2*)&y[(long)id[u] * HID + j]);
            acc0 += g.x; acc1 += g.y;
        }
        e += 16;
    } while (e < e1);

    const float ni = norm[i];
    float2 bi = *(const float2*)&bias[j];
    float2 me = *(const float2*)&mean[j];
    float2 ga = *(const float2*)&gamma[j];
    float2 va = *(const float2*)&var[j];
    float2 be = *(const float2*)&beta[j];
    float v0 = (acc0 * ni + bi.x - me.x) * (ga.x * rsqrtf(va.x + BN_EPS_C)) + be.x;
    float v1 = (acc1 * ni + bi.y - me.y) * (ga.y * rsqrtf(va.y + BN_EPS_C)) + be.y;
    *(__half2*)&h[(long)i * HID + j] = __floats2half2_rn(fmaxf(v0, 0.f), fmaxf(v1, 0.f));
}

// ---------------- Pooling (batch sorted -> run-length local accumulation) ----------------
// 32 nodes per block (3125 blocks) for occupancy; boundary runs merged via atomics.

__global__ __launch_bounds__(128) void k_pool(const __half* __restrict__ h, const int* __restrict__ batch,
                                              float* __restrict__ psum, int* __restrict__ pcount) {
    const int j = threadIdx.x;
    const int i0 = blockIdx.x * 32;
    const int iend = min(i0 + 32, N_NODES_C);
    if (i0 >= N_NODES_C) return;
    float acc = 0.f;
    int cur = batch[i0];
    int runStart = i0;
    for (int i = i0; i < iend; i++) {
        int g = batch[i];
        if (g != cur) {
            atomicAdd(&psum[(long)cur * HID + j], acc);
            if (j == 0) atomicAdd(&pcount[cur], i - runStart);
            acc = 0.f; cur = g; runStart = i;
        }
        acc += __half2float(h[(long)i * HID + j]);
    }
    atomicAdd(&psum[(long)cur * HID + j], acc);
    if (j == 0) atomicAdd(&pcount[cur], iend - runStart);
}

__global__ __launch_bounds__(128) void k_final(const float* __restrict__ psum, const int* __restrict__ pcount,
                                               const float* __restrict__ W_out, const float* __restrict__ b_out,
                                               float* __restrict__ out) {
    __shared__ float red[128][5];
    const int g = blockIdx.x, j = threadIdx.x;
    float cnt = fmaxf((float)pcount[g], 1.f);
    float p = psum[(long)g * HID + j] / cnt;
    #pragma unroll
    for (int o = 0; o < 5; o++) red[j][o] = p * W_out[j * 5 + o];
    __syncthreads();
    for (int off = 64; off >= 1; off >>= 1) {
        if (j < off) {
            #pragma unroll
            for (int o = 0; o < 5; o++) red[j][o] += red[j + off][o];
        }
        __syncthreads();
    }
    if (j < 5) out[g * 5 + j] = red[0][j] + b_out[j];
}

// ---------------- launch ----------------

extern "C" void kernel_launch(void* const* d_in, const int* in_sizes, int n_in,
                              void* d_out, int out_size, void* d_ws, size_t ws_size,
                              hipStream_t stream) {
    const float* x        = (const float*)d_in[0];
    const int*   eidx     = (const int*)d_in[1];
    const int*   src      = eidx;
    const int*   dst      = eidx + N_EDGES_C;
    const int*   batch    = (const int*)d_in[2];
    const float* Ws_all   = (const float*)d_in[3];
    const float* bs       = (const float*)d_in[4];
    const float* gammas   = (const float*)d_in[5];
    const float* betas    = (const float*)d_in[6];
    const float* run_mean = (const float*)d_in[7];
    const float* run_var  = (const float*)d_in[8];
    const float* W_out    = (const float*)d_in[9];
    const float* b_out    = (const float*)d_in[10];
    float* out = (float*)d_out;

    char* wp = (char*)d_ws;
    auto alloc = [&](size_t bytes) { char* p = wp; wp += (bytes + 255) & ~(size_t)255; return p; };
    __half*   h       = (__half*)alloc((size_t)N_NODES_C * HID * 2);
    _Float16* y       = (_Float16*)alloc((size_t)(N_NODES_C + 128) * HID * 2);  // +pad rows; dummy row N_NODES zeroed by k_gemm
    int*      ebuf    = (int*)y;                 // alias: packed 4B entries, dead before first k_gemm
    _Float16* WT      = (_Float16*)alloc((size_t)4 * HID * HID * 2);
    int*      csr_src = (int*)alloc((size_t)(N_EDGES_C + 16) * 4);  // +16 pad for 16-wide chain overread (read, cselect-discarded)
    int*      offs    = (int*)alloc((size_t)(N_NODES_C + 1) * 4);
    float*    norm    = (float*)alloc((size_t)N_NODES_C * 4);
    int*      bbase   = (int*)alloc((NBUCK + 1) * 4);
    int*      bcursor = (int*)alloc((NBUCK + 1) * 4);
    // zero-init group: psum | pcount | bcount contiguous -> ONE memset
    char*     zbeg    = wp;
    float*    psum    = (float*)alloc((size_t)N_GRAPHS_C * HID * 4);
    int*      pcount  = (int*)alloc((size_t)N_GRAPHS_C * 4);
    int*      bcount  = (int*)alloc((NBUCK + 1) * 4);
    size_t    zlen    = (size_t)(wp - zbeg);

    hipMemsetAsync(zbeg, 0, zlen, stream);   // psum + pcount + bcount in one shot

    k_tw<<<256, 256, 0, stream>>>(Ws_all, WT);

    const int PB = (N_EDGES_C + PART_TILE - 1) / PART_TILE;  // 391
    kb_hist<<<PB, 256, 0, stream>>>(dst, bcount);
    kb_scan<<<1, 512, 0, stream>>>(bcount, bbase, bcursor);
    kb_part<<<PB, 256, 0, stream>>>(src, dst, bcursor, ebuf);
    kb_fill<<<NBUCK, 256, 0, stream>>>(ebuf, bbase, csr_src, offs, norm);

    const int GB = (N_NODES_C + 127) / 128;   // 782
    const int AB = (N_NODES_C + 3) / 4;       // 25000
    for (int l = 0; l < 4; l++) {
        const void* A = (l == 0) ? (const void*)x : (const void*)h;
        if (l == 0)
            k_gemm<true><<<GB, 256, 0, stream>>>(A, WT, norm, y, N_NODES_C);
        else
            k_gemm<false><<<GB, 256, 0, stream>>>(A, WT + (size_t)l * HID * HID, norm, y, N_NODES_C);
        k_agg<<<AB, 256, 0, stream>>>((const __half*)y, offs, csr_src, norm,
                                      bs + l * HID, run_mean + l * HID, gammas + l * HID,
                                      run_var + l * HID, betas + l * HID, (__half*)h);
    }
    const int PB2 = (N_NODES_C + 31) / 32;    // 3125
    k_pool <<<PB2, 128, 0, stream>>>((const __half*)h, batch, psum, pcount);
    k_final<<<N_GRAPHS_C, 128, 0, stream>>>(psum, pcount, W_out, b_out, out);
}